// Round 1
// baseline (1445.072 us; speedup 1.0000x reference)
//
#include <hip/hip_runtime.h>
#include <cstddef>

#define BATCH 32
#define CCH   512
#define OCH   1024
#define HW    3136
#define WDIM  56

// ---------------------------------------------------------------------------
// K1: per-batch GEMM  x[b,o,n] = sum_c w[o,c] * in[b,c,n] + bias[o]
// BM=128 (o), BN=64 (n), BK=16, 256 threads, 8x4 micro-tile per thread.
// o < 512  -> gate  (stored temporarily in d_out)
// o >= 512 -> scan  (stored in d_ws)
// ---------------------------------------------------------------------------
__global__ __launch_bounds__(256) void gemm_proj(
    const float* __restrict__ in,    // [B,512,3136]
    const float* __restrict__ wp,    // [1024,512] row-major [o,c]
    const float* __restrict__ bp,    // [1024]
    float* __restrict__ gate,        // [B,512,3136]
    float* __restrict__ scan)        // [B,512,3136]
{
    const int bx = blockIdx.x;   // 0..48  (n tiles)
    const int by = blockIdx.y;   // 0..7   (o tiles)
    const int b  = blockIdx.z;   // batch
    const int t  = threadIdx.x;

    __shared__ float As[16][128];   // [k][o]
    __shared__ float Bs[16][64];    // [k][n]

    const float* Ab = wp + (size_t)(by * 128) * CCH;
    const float* Bb = in + (size_t)b * CCH * HW + bx * 64;

    float acc[8][4];
#pragma unroll
    for (int i = 0; i < 8; i++)
#pragma unroll
        for (int j = 0; j < 4; j++) acc[i][j] = 0.f;

    const int a_row = t >> 1;        // 0..127
    const int a_c   = (t & 1) * 8;   // 0 or 8
    const int b_row = t >> 4;        // 0..15
    const int b_n   = (t & 15) * 4;  // 0..60
    const int ty    = t >> 4;        // 0..15 -> row0 = ty*8
    const int tx    = t & 15;        // 0..15 -> col0 = tx*4

    for (int k0 = 0; k0 < CCH; k0 += 16) {
        float4 av0 = *(const float4*)(Ab + (size_t)a_row * CCH + k0 + a_c);
        float4 av1 = *(const float4*)(Ab + (size_t)a_row * CCH + k0 + a_c + 4);
        float4 bv  = *(const float4*)(Bb + (size_t)(k0 + b_row) * HW + b_n);
        __syncthreads();
        As[a_c + 0][a_row] = av0.x; As[a_c + 1][a_row] = av0.y;
        As[a_c + 2][a_row] = av0.z; As[a_c + 3][a_row] = av0.w;
        As[a_c + 4][a_row] = av1.x; As[a_c + 5][a_row] = av1.y;
        As[a_c + 6][a_row] = av1.z; As[a_c + 7][a_row] = av1.w;
        *(float4*)&Bs[b_row][b_n] = bv;
        __syncthreads();
#pragma unroll
        for (int kk = 0; kk < 16; kk++) {
            float4 a0 = *(const float4*)&As[kk][ty * 8];
            float4 a1 = *(const float4*)&As[kk][ty * 8 + 4];
            float4 bb = *(const float4*)&Bs[kk][tx * 4];
            float av[8] = {a0.x, a0.y, a0.z, a0.w, a1.x, a1.y, a1.z, a1.w};
            float bw[4] = {bb.x, bb.y, bb.z, bb.w};
#pragma unroll
            for (int i = 0; i < 8; i++)
#pragma unroll
                for (int j = 0; j < 4; j++)
                    acc[i][j] = fmaf(av[i], bw[j], acc[i][j]);
        }
    }

    const int n0 = bx * 64 + tx * 4;
#pragma unroll
    for (int i = 0; i < 8; i++) {
        const int o = by * 128 + ty * 8 + i;
        const float bias = bp[o];
        float4 v;
        v.x = acc[i][0] + bias; v.y = acc[i][1] + bias;
        v.z = acc[i][2] + bias; v.w = acc[i][3] + bias;
        float* dst;
        if (o < CCH) dst = gate + ((size_t)b * CCH + o) * HW + n0;
        else         dst = scan + ((size_t)b * CCH + (o - CCH)) * HW + n0;
        *(float4*)dst = v;
    }
}

// ---------------------------------------------------------------------------
// K2: per-(b,c) 2D discounted scan + fused epilogue.
// One wave (64 threads) per 56x56 image. gate_out = d_out: holds gate on
// entry, overwritten with the final result (same-index read-then-write).
// ---------------------------------------------------------------------------
__global__ __launch_bounds__(64) void scan_fuse(
    const float* __restrict__ in,      // [B,512,3136]
    const float* __restrict__ scanb,   // [B,512,3136] x_scan
    const float* __restrict__ disc,    // [512]
    const float* __restrict__ gamma,   // [1]
    float* gate_out)                   // [B,512,3136] gate in, result out
{
    const int idx = blockIdx.x;            // b*512 + c
    const int c = idx & (CCH - 1);
    const size_t base = (size_t)idx * HW;
    const float d = disc[c];
    const float g = gamma[0];
    const int lane = threadIdx.x;

    __shared__ float L[WDIM * 57];

    // Phase 1: scan along h (lane = w). Coalesced loads row by row.
    if (lane < WDIM) {
        const int w = lane;
        float acc = 0.f;
#pragma unroll 4
        for (int h = 0; h < WDIM; h++) {
            acc = fmaf(d, acc, scanb[base + h * WDIM + w]);
            L[h * 57 + w] = acc;
        }
    }
    __syncthreads();

    // Phase 2: scan along w (lane = h). Stride 57 -> conflict-free.
    if (lane < WDIM) {
        const int h = lane;
        float acc = 0.f;
#pragma unroll 4
        for (int w = 0; w < WDIM; w++) {
            acc = fmaf(d, acc, L[h * 57 + w]);
            L[h * 57 + w] = acc;
        }
    }
    __syncthreads();

    // Phase 3: fused epilogue, coalesced (lane = w).
    if (lane < WDIM) {
        const int w = lane;
#pragma unroll 4
        for (int h = 0; h < WDIM; h++) {
            const size_t off = base + h * WDIM + w;
            const float xc = L[h * 57 + w];
            const float sg = 1.f / (1.f + __expf(-xc));
            const float val = fmaf(g * gate_out[off], sg, in[off]);
            gate_out[off] = val;
        }
    }
}

extern "C" void kernel_launch(void* const* d_in, const int* in_sizes, int n_in,
                              void* d_out, int out_size, void* d_ws, size_t ws_size,
                              hipStream_t stream) {
    const float* in = (const float*)d_in[0];
    const float* wp = (const float*)d_in[1];
    const float* bp = (const float*)d_in[2];
    const float* dc = (const float*)d_in[3];
    const float* gm = (const float*)d_in[4];
    float* out = (float*)d_out;
    float* ws  = (float*)d_ws;   // 32*512*3136*4 = 196 MB for x_scan

    dim3 g1(HW / 64, OCH / 128, BATCH);
    gemm_proj<<<g1, 256, 0, stream>>>(in, wp, bp, out, ws);

    scan_fuse<<<BATCH * CCH, 64, 0, stream>>>(in, ws, dc, gm, out);
}

// Round 2
// 1297.940 us; speedup vs baseline: 1.1134x; 1.1134x over previous
//
#include <hip/hip_runtime.h>
#include <cstddef>

#define BATCH 32
#define CCH   512
#define OCH   1024
#define HW    3136
#define WDIM  56
#define BK    32
#define NT    16   // 512 / BK

typedef __attribute__((ext_vector_type(8))) short short8v;  // 8 bf16 (4 VGPRs)
typedef __attribute__((ext_vector_type(4))) float f32x4;

// pair of fp32 -> packed bf16 hi-word + lo-word.
// hi = truncate(x) (sign-symmetric, compensated by lo); lo = RNE(x - hi).
static __device__ __forceinline__ void cvt2(float x0, float x1,
                                            unsigned& hw, unsigned& lw) {
    unsigned u0 = __float_as_uint(x0), u1 = __float_as_uint(x1);
    hw = (u1 & 0xffff0000u) | (u0 >> 16);
    float l0 = x0 - __uint_as_float(u0 & 0xffff0000u);
    float l1 = x1 - __uint_as_float(u1 & 0xffff0000u);
    unsigned r0 = __float_as_uint(l0), r1 = __float_as_uint(l1);
    r0 = r0 + 0x7fffu + ((r0 >> 16) & 1u);
    r1 = r1 + 0x7fffu + ((r1 >> 16) & 1u);
    lw = (r1 & 0xffff0000u) | (r0 >> 16);
}

// ---------------------------------------------------------------------------
// MFMA GEMM: x[b,o,n] = sum_c w[o,c]*in[b,c,n] + bias[o], bf16 hi/lo split.
// Block tile 128(o) x 128(n), BK=32, 256 threads = 4 waves (2x2 of 64x64).
// LDS rows: 128B per (row, K-tile): slots 0-3 = hi k-octets, 4-7 = lo,
// physical slot = (slot ^ (row&7) ^ ((row>>3)&7)) & 7  (both write & read).
// ---------------------------------------------------------------------------
__global__ __launch_bounds__(256, 2) void gemm_mfma(
    const float* __restrict__ in,    // [B,512,3136]
    const float* __restrict__ wp,    // [1024,512]
    const float* __restrict__ bp,    // [1024]
    float* __restrict__ gate,        // [B,512,3136] (d_out temp)
    float* __restrict__ scan)        // [B,512,3136] (ws)
{
    const int bx = blockIdx.x;   // 0..24  n-tiles (last is half)
    const int by = blockIdx.y;   // 0..7   o-tiles
    const int b  = blockIdx.z;
    const int t  = threadIdx.x;
    const int lane = t & 63;
    const int wid  = t >> 6;
    const int wm = wid >> 1, wn = wid & 1;
    const int l15 = lane & 15, lko = lane >> 4;   // frag col/row & k-octet

    __shared__ __align__(16) unsigned char lds[32768];
    unsigned char* ldsA = lds;            // 128 rows x 128B
    unsigned char* ldsB = lds + 16384;    // 128 rows x 128B

    const int o0 = by * 128;
    const int n0 = bx * 128;

    // --- staging roles ---
    const bool isB = (t < 128);
    // B role: thread (q, ko): 8 k-rows x 4 n-cols
    const int q  = t & 31;
    const int ko = (t >> 5) & 3;
    const int maxq = ((HW - n0) >> 2) - 1;
    const int qc = q < maxq ? q : maxq;                 // clamp tail loads
    const float* gB = in + (size_t)b * (CCH * (size_t)HW) + n0 + 4 * qc;
    // A role: thread ua: one o-row, 32 k
    const int ua = t & 127;
    const float* gA = wp + (size_t)(o0 + ua) * CCH;

    float4 regs[8];

    auto load_stage = [&](int kt) {
        if (isB) {
            const float* p = gB + (size_t)(kt * BK + ko * 8) * HW;
#pragma unroll
            for (int r = 0; r < 8; ++r)
                regs[r] = *(const float4*)(p + (size_t)r * HW);
        } else {
            const float* p = gA + kt * BK;
#pragma unroll
            for (int k2 = 0; k2 < 4; ++k2) {
                regs[2 * k2]     = *(const float4*)(p + k2 * 8);
                regs[2 * k2 + 1] = *(const float4*)(p + k2 * 8 + 4);
            }
        }
    };

    auto write_stage = [&]() {
        if (isB) {
            // transpose in registers: column c of the 8x4 block -> 8 k-contig bf16
#define B_COL(CIDX, COMP) { \
            const int nl = 4 * q + CIDX; \
            unsigned h0, w0, h1, w1, h2, w2, h3, w3; \
            cvt2(regs[0].COMP, regs[1].COMP, h0, w0); \
            cvt2(regs[2].COMP, regs[3].COMP, h1, w1); \
            cvt2(regs[4].COMP, regs[5].COMP, h2, w2); \
            cvt2(regs[6].COMP, regs[7].COMP, h3, w3); \
            const int sw = (nl & 7) ^ ((nl >> 3) & 7); \
            *(uint4*)(ldsB + nl * 128 + (((ko) ^ sw) & 7) * 16)     = make_uint4(h0, h1, h2, h3); \
            *(uint4*)(ldsB + nl * 128 + (((4 + ko) ^ sw) & 7) * 16) = make_uint4(w0, w1, w2, w3); \
            }
            B_COL(0, x) B_COL(1, y) B_COL(2, z) B_COL(3, w)
#undef B_COL
        } else {
            const int sw = (ua & 7) ^ ((ua >> 3) & 7);
#pragma unroll
            for (int k2 = 0; k2 < 4; ++k2) {
                unsigned h0, w0, h1, w1, h2, w2, h3, w3;
                cvt2(regs[2 * k2].x,     regs[2 * k2].y,     h0, w0);
                cvt2(regs[2 * k2].z,     regs[2 * k2].w,     h1, w1);
                cvt2(regs[2 * k2 + 1].x, regs[2 * k2 + 1].y, h2, w2);
                cvt2(regs[2 * k2 + 1].z, regs[2 * k2 + 1].w, h3, w3);
                *(uint4*)(ldsA + ua * 128 + ((k2 ^ sw) & 7) * 16)       = make_uint4(h0, h1, h2, h3);
                *(uint4*)(ldsA + ua * 128 + (((4 + k2) ^ sw) & 7) * 16) = make_uint4(w0, w1, w2, w3);
            }
        }
    };

    f32x4 acc[4][4] = {};

    load_stage(0);
#pragma unroll 1
    for (int kt = 0; kt < NT; ++kt) {
        write_stage();
        __syncthreads();
        if (kt + 1 < NT) load_stage(kt + 1);   // issue early, hides under MFMA

        short8v afr[2][4], bfr[2][4];
#pragma unroll
        for (int f = 0; f < 4; ++f) {
            const int r = wm * 64 + f * 16 + l15;
            const int sw = (r & 7) ^ ((r >> 3) & 7);
            afr[0][f] = *(const short8v*)(ldsA + r * 128 + ((lko ^ sw) & 7) * 16);
            afr[1][f] = *(const short8v*)(ldsA + r * 128 + (((4 + lko) ^ sw) & 7) * 16);
        }
#pragma unroll
        for (int g = 0; g < 4; ++g) {
            const int n = wn * 64 + g * 16 + l15;
            const int sw = (n & 7) ^ ((n >> 3) & 7);
            bfr[0][g] = *(const short8v*)(ldsB + n * 128 + ((lko ^ sw) & 7) * 16);
            bfr[1][g] = *(const short8v*)(ldsB + n * 128 + (((4 + lko) ^ sw) & 7) * 16);
        }
#pragma unroll
        for (int f = 0; f < 4; ++f)
#pragma unroll
            for (int g = 0; g < 4; ++g) {
                acc[f][g] = __builtin_amdgcn_mfma_f32_16x16x32_bf16(afr[0][f], bfr[0][g], acc[f][g], 0, 0, 0);
                acc[f][g] = __builtin_amdgcn_mfma_f32_16x16x32_bf16(afr[1][f], bfr[0][g], acc[f][g], 0, 0, 0);
                acc[f][g] = __builtin_amdgcn_mfma_f32_16x16x32_bf16(afr[0][f], bfr[1][g], acc[f][g], 0, 0, 0);
            }
        __syncthreads();
    }

    // --- epilogue: bias + route to gate/scan; C row=(lane>>4)*4+reg, col=lane&15
    float* base = (by < 4) ? gate : scan;
    const int c0 = (o0 & (CCH - 1));
#pragma unroll
    for (int f = 0; f < 4; ++f) {
        const int rowb = wm * 64 + f * 16 + lko * 4;
#pragma unroll
        for (int rg = 0; rg < 4; ++rg) {
            const float bias = bp[o0 + rowb + rg];
            float* drow = base + ((size_t)b * CCH + c0 + rowb + rg) * HW;
#pragma unroll
            for (int g = 0; g < 4; ++g) {
                const int n = n0 + wn * 64 + g * 16 + l15;
                if (n < HW) drow[n] = acc[f][g][rg] + bias;
            }
        }
    }
}

// ---------------------------------------------------------------------------
// K2: per-(b,c) 2D discounted scan + fused epilogue (unchanged from R0).
// ---------------------------------------------------------------------------
__global__ __launch_bounds__(64) void scan_fuse(
    const float* __restrict__ in,
    const float* __restrict__ scanb,
    const float* __restrict__ disc,
    const float* __restrict__ gamma,
    float* gate_out)
{
    const int idx = blockIdx.x;
    const int c = idx & (CCH - 1);
    const size_t base = (size_t)idx * HW;
    const float d = disc[c];
    const float g = gamma[0];
    const int lane = threadIdx.x;

    __shared__ float L[WDIM * 57];

    if (lane < WDIM) {
        const int w = lane;
        float acc = 0.f;
#pragma unroll 4
        for (int h = 0; h < WDIM; h++) {
            acc = fmaf(d, acc, scanb[base + h * WDIM + w]);
            L[h * 57 + w] = acc;
        }
    }
    __syncthreads();
    if (lane < WDIM) {
        const int h = lane;
        float acc = 0.f;
#pragma unroll 4
        for (int w = 0; w < WDIM; w++) {
            acc = fmaf(d, acc, L[h * 57 + w]);
            L[h * 57 + w] = acc;
        }
    }
    __syncthreads();
    if (lane < WDIM) {
        const int w = lane;
#pragma unroll 4
        for (int h = 0; h < WDIM; h++) {
            const size_t off = base + h * WDIM + w;
            const float xc = L[h * 57 + w];
            const float sg = 1.f / (1.f + __expf(-xc));
            const float val = fmaf(g * gate_out[off], sg, in[off]);
            gate_out[off] = val;
        }
    }
}

extern "C" void kernel_launch(void* const* d_in, const int* in_sizes, int n_in,
                              void* d_out, int out_size, void* d_ws, size_t ws_size,
                              hipStream_t stream) {
    const float* in = (const float*)d_in[0];
    const float* wp = (const float*)d_in[1];
    const float* bp = (const float*)d_in[2];
    const float* dc = (const float*)d_in[3];
    const float* gm = (const float*)d_in[4];
    float* out = (float*)d_out;
    float* ws  = (float*)d_ws;   // x_scan: 205 MB

    dim3 g1((HW + 127) / 128, OCH / 128, BATCH);
    gemm_mfma<<<g1, 256, 0, stream>>>(in, wp, bp, out, ws);

    scan_fuse<<<BATCH * CCH, 64, 0, stream>>>(in, ws, dc, gm, out);
}

// Round 3
// 661.794 us; speedup vs baseline: 2.1836x; 1.9612x over previous
//
#include <hip/hip_runtime.h>
#include <cstddef>
#include <cstdint>

#define BATCH 32
#define CCH   512
#define OCH   1024
#define HW    3136
#define WDIM  56
#define NKT   16           // 512 / BK, BK=32

typedef __attribute__((ext_vector_type(8))) short short8v;  // 8 bf16
typedef __attribute__((ext_vector_type(4))) float f32x4;

// pair of fp32 -> packed bf16 hi-word + lo-word (R1-proven numerics).
static __device__ __forceinline__ void cvt2(float x0, float x1,
                                            unsigned& hw, unsigned& lw) {
    unsigned u0 = __float_as_uint(x0), u1 = __float_as_uint(x1);
    hw = (u1 & 0xffff0000u) | (u0 >> 16);
    float l0 = x0 - __uint_as_float(u0 & 0xffff0000u);
    float l1 = x1 - __uint_as_float(u1 & 0xffff0000u);
    unsigned r0 = __float_as_uint(l0), r1 = __float_as_uint(l1);
    r0 = r0 + 0x7fffu + ((r0 >> 16) & 1u);
    r1 = r1 + 0x7fffu + ((r1 >> 16) & 1u);
    lw = (r1 & 0xffff0000u) | (r0 >> 16);
}

static __device__ __forceinline__ int physlot(int s, int row) {
    return (s ^ (row & 7) ^ ((row >> 3) & 7)) & 7;
}

#define GLD_LDS16(gsrc, ldst) \
    __builtin_amdgcn_global_load_lds( \
        (const __attribute__((address_space(1))) void*)(gsrc), \
        (__attribute__((address_space(3))) void*)(ldst), 16, 0, 0)

// ---------------------------------------------------------------------------
// K0: pre-convert weights into LDS-image layout:
// wcvt[o][kt] = 128 B: phys slots 0-3 <- hi octets 0-3, 4-7 <- lo octets,
// pre-swizzled with the same physlot(s, o mod 512) the GEMM uses.
// ---------------------------------------------------------------------------
__global__ __launch_bounds__(256) void preconv_w(
    const float* __restrict__ wp, unsigned char* __restrict__ wcvt)
{
    const int id = blockIdx.x * 256 + threadIdx.x;   // 16384 = 1024 o x 16 kt
    const int o = id >> 4, kt = id & 15;
    const float* p = wp + (size_t)o * CCH + kt * 32;
    unsigned char* dst = wcvt + (size_t)o * 2048 + kt * 128;
    float4 v[8];
#pragma unroll
    for (int r = 0; r < 8; ++r) v[r] = *(const float4*)(p + 4 * r);
#pragma unroll
    for (int oc = 0; oc < 4; ++oc) {
        unsigned h0, w0, h1, w1, h2, w2, h3, w3;
        cvt2(v[2*oc].x,   v[2*oc].y,   h0, w0);
        cvt2(v[2*oc].z,   v[2*oc].w,   h1, w1);
        cvt2(v[2*oc+1].x, v[2*oc+1].y, h2, w2);
        cvt2(v[2*oc+1].z, v[2*oc+1].w, h3, w3);
        *(uint4*)(dst + physlot(oc, o) * 16)     = make_uint4(h0, h1, h2, h3);
        *(uint4*)(dst + physlot(4 + oc, o) * 16) = make_uint4(w0, w1, w2, w3);
    }
}

// ---------------------------------------------------------------------------
// K1: MFMA GEMM, tile 512(o) x 128(n), BK=32, 512 threads = 8 waves (4x2).
// by=0 -> gate half (d_out), by=1 -> scan half (ws).
// A staged via global_load_lds from pre-converted weights (PRE=true) or
// converted per-step in registers (fallback). B reg-staged with prefetch.
// ---------------------------------------------------------------------------
template <bool PRE>
__global__ __launch_bounds__(512, 2) void gemm_mfma(
    const float* __restrict__ in,          // [B,512,3136]
    const float* __restrict__ wp,          // [1024,512] (fallback path)
    const unsigned char* __restrict__ wc,  // wcvt (fast path)
    const float* __restrict__ bp,          // [1024]
    float* __restrict__ gate,              // d_out
    float* __restrict__ scan)              // ws (+2MB on fast path)
{
    const int bx = blockIdx.x;   // 0..24 n-tiles of 128 (last is half)
    const int by = blockIdx.y;   // 0: gate, 1: scan
    const int b  = blockIdx.z;
    const int t  = threadIdx.x;
    const int lane = t & 63;
    const int wid  = t >> 6;           // 0..7
    const int wm = wid >> 1;           // o-strip of 128 (0..3)
    const int wn = wid & 1;            // n-strip of 64
    const int l15 = lane & 15, lko = lane >> 4;

    __shared__ __align__(16) unsigned char lds[81920];   // A 64K | B 16K
    unsigned char* ldsB = lds + 65536;

    const int o0 = by * 512;
    const int n0 = bx * 128;

    // B staging role: thread (q = n-quad, kk = k-pair)
    const int q  = t & 31;
    const int kk = t >> 5;             // 0..15
    const int maxq = ((HW - n0) >> 2) - 1;
    const int qc = q < maxq ? q : maxq;
    const float* inB = in + (size_t)b * (CCH * (size_t)HW) + n0 + 4 * qc;

    f32x4 acc[8][4] = {};

    float4 bc0, bc1, bn0, bn1;
    {   // B(0)
        const float* p = inB + (size_t)(2 * kk) * HW;
        bc0 = *(const float4*)p;
        bc1 = *(const float4*)(p + HW);
    }

#pragma unroll 1
    for (int kt = 0; kt < NKT; ++kt) {
        // ---- write B(kt) to LDS (8x b32) ----
        {
            unsigned char* rowb;
            unsigned hw_, lw_;
            const int oc = kk >> 2, j4 = (kk & 3) * 4;
#define BCOL(C, COMP) \
            { const int nl = 4 * q + C; \
              cvt2(bc0.COMP, bc1.COMP, hw_, lw_); \
              rowb = ldsB + nl * 128; \
              *(unsigned*)(rowb + physlot(oc, nl) * 16 + j4)     = hw_; \
              *(unsigned*)(rowb + physlot(4 + oc, nl) * 16 + j4) = lw_; }
            BCOL(0, x) BCOL(1, y) BCOL(2, z) BCOL(3, w)
#undef BCOL
        }

        // ---- stage A(kt) ----
        if constexpr (PRE) {
            // linear copy of 512 rows x 128B from wcvt via global_load_lds
            const unsigned char* srcb = wc + (size_t)o0 * 2048 + kt * 128;
            const int sub = (t & 7) * 16;          // byte within row
            const int rbase = t >> 3;              // row contribution of t
#pragma unroll
            for (int j = 0; j < 8; ++j) {
                const int row = j * 64 + rbase;
                void* dstu = lds + j * 8192 + wid * 1024;  // wave-uniform
                GLD_LDS16(srcb + (size_t)row * 2048 + sub, dstu);
            }
        } else {
            const float* p = wp + (size_t)(o0 + t) * CCH + kt * 32;
            float4 av[8];
#pragma unroll
            for (int r = 0; r < 8; ++r) av[r] = *(const float4*)(p + 4 * r);
            unsigned char* rowa = lds + t * 128;
#pragma unroll
            for (int oc = 0; oc < 4; ++oc) {
                unsigned h0, w0, h1, w1, h2, w2, h3, w3;
                cvt2(av[2*oc].x,   av[2*oc].y,   h0, w0);
                cvt2(av[2*oc].z,   av[2*oc].w,   h1, w1);
                cvt2(av[2*oc+1].x, av[2*oc+1].y, h2, w2);
                cvt2(av[2*oc+1].z, av[2*oc+1].w, h3, w3);
                *(uint4*)(rowa + physlot(oc, t) * 16)     = make_uint4(h0, h1, h2, h3);
                *(uint4*)(rowa + physlot(4 + oc, t) * 16) = make_uint4(w0, w1, w2, w3);
            }
        }

        asm volatile("" ::: "memory");   // pin: staging above, prefetch below

        // ---- prefetch B(kt+1) into regs; counted vmcnt keeps it in flight ----
        if (kt + 1 < NKT) {
            const float* p = inB + (size_t)((kt + 1) * 32 + 2 * kk) * HW;
            bn0 = *(const float4*)p;
            bn1 = *(const float4*)(p + HW);
            if constexpr (PRE) asm volatile("s_waitcnt vmcnt(2)" ::: "memory");
        } else {
            if constexpr (PRE) asm volatile("s_waitcnt vmcnt(0)" ::: "memory");
        }
        asm volatile("s_waitcnt lgkmcnt(0)" ::: "memory");
        __builtin_amdgcn_s_barrier();
        asm volatile("" ::: "memory");

        // ---- fragments + MFMA ----
        short8v bfh[4], bfl[4];
#pragma unroll
        for (int g = 0; g < 4; ++g) {
            const int n = wn * 64 + g * 16 + l15;
            const unsigned char* rb = ldsB + n * 128;
            bfh[g] = *(const short8v*)(rb + physlot(lko, n) * 16);
            bfl[g] = *(const short8v*)(rb + physlot(4 + lko, n) * 16);
        }
#pragma unroll
        for (int fh = 0; fh < 2; ++fh) {
            short8v ah[4], al[4];
#pragma unroll
            for (int fi = 0; fi < 4; ++fi) {
                const int r = wm * 128 + (fh * 4 + fi) * 16 + l15;
                const unsigned char* ra = lds + r * 128;
                ah[fi] = *(const short8v*)(ra + physlot(lko, r) * 16);
                al[fi] = *(const short8v*)(ra + physlot(4 + lko, r) * 16);
            }
#pragma unroll
            for (int fi = 0; fi < 4; ++fi)
#pragma unroll
                for (int g = 0; g < 4; ++g) {
                    f32x4 c = acc[fh * 4 + fi][g];
                    c = __builtin_amdgcn_mfma_f32_16x16x32_bf16(ah[fi], bfh[g], c, 0, 0, 0);
                    c = __builtin_amdgcn_mfma_f32_16x16x32_bf16(al[fi], bfh[g], c, 0, 0, 0);
                    c = __builtin_amdgcn_mfma_f32_16x16x32_bf16(ah[fi], bfl[g], c, 0, 0, 0);
                    acc[fh * 4 + fi][g] = c;
                }
        }

        asm volatile("" ::: "memory");
        __builtin_amdgcn_s_barrier();
        asm volatile("" ::: "memory");

        bc0 = bn0; bc1 = bn1;
    }

    // ---- epilogue: bias + store (C: row = lko*4+rg, col = l15) ----
    float* dstb = (by == 0) ? gate : scan;
#pragma unroll
    for (int f = 0; f < 8; ++f) {
        const int rowb = wm * 128 + f * 16 + lko * 4;
#pragma unroll
        for (int rg = 0; rg < 4; ++rg) {
            const int o = o0 + rowb + rg;
            const float bias = bp[o];
            float* drow = dstb + ((size_t)b * CCH + (o & (CCH - 1))) * HW;
#pragma unroll
            for (int g = 0; g < 4; ++g) {
                const int n = n0 + wn * 64 + g * 16 + l15;
                if (n < HW) drow[n] = acc[f][g][rg] + bias;
            }
        }
    }
}

// ---------------------------------------------------------------------------
// K2: per-(b,c) 2D discounted scan + fused epilogue (R0-proven).
// ---------------------------------------------------------------------------
__global__ __launch_bounds__(64) void scan_fuse(
    const float* __restrict__ in,
    const float* __restrict__ scanb,
    const float* __restrict__ disc,
    const float* __restrict__ gamma,
    float* gate_out)
{
    const int idx = blockIdx.x;
    const int c = idx & (CCH - 1);
    const size_t base = (size_t)idx * HW;
    const float d = disc[c];
    const float g = gamma[0];
    const int lane = threadIdx.x;

    __shared__ float L[WDIM * 57];

    if (lane < WDIM) {
        const int w = lane;
        float acc = 0.f;
#pragma unroll 4
        for (int h = 0; h < WDIM; h++) {
            acc = fmaf(d, acc, scanb[base + h * WDIM + w]);
            L[h * 57 + w] = acc;
        }
    }
    __syncthreads();
    if (lane < WDIM) {
        const int h = lane;
        float acc = 0.f;
#pragma unroll 4
        for (int w = 0; w < WDIM; w++) {
            acc = fmaf(d, acc, L[h * 57 + w]);
            L[h * 57 + w] = acc;
        }
    }
    __syncthreads();
    if (lane < WDIM) {
        const int w = lane;
#pragma unroll 4
        for (int h = 0; h < WDIM; h++) {
            const size_t off = base + h * WDIM + w;
            const float xc = L[h * 57 + w];
            const float sg = 1.f / (1.f + __expf(-xc));
            const float val = fmaf(g * gate_out[off], sg, in[off]);
            gate_out[off] = val;
        }
    }
}

extern "C" void kernel_launch(void* const* d_in, const int* in_sizes, int n_in,
                              void* d_out, int out_size, void* d_ws, size_t ws_size,
                              hipStream_t stream) {
    const float* in = (const float*)d_in[0];
    const float* wp = (const float*)d_in[1];
    const float* bp = (const float*)d_in[2];
    const float* dc = (const float*)d_in[3];
    const float* gm = (const float*)d_in[4];
    float* out = (float*)d_out;

    const size_t scan_bytes = (size_t)BATCH * CCH * HW * 4;   // 205.5 MB
    const size_t wcvt_bytes = (size_t)OCH * CCH * 4;          // 2 MB
    const bool pre = ws_size >= scan_bytes + wcvt_bytes;

    unsigned char* wcvt = (unsigned char*)d_ws;
    float* scanp = (float*)((unsigned char*)d_ws + (pre ? wcvt_bytes : 0));

    dim3 g1(25, 2, BATCH);
    if (pre) {
        preconv_w<<<64, 256, 0, stream>>>(wp, wcvt);
        gemm_mfma<true><<<g1, 512, 0, stream>>>(in, wp, wcvt, bp, out, scanp);
    } else {
        gemm_mfma<false><<<g1, 512, 0, stream>>>(in, wp, wcvt, bp, out, scanp);
    }

    scan_fuse<<<BATCH * CCH, 64, 0, stream>>>(in, scanp, dc, gm, out);
}